// Round 8
// baseline (565.401 us; speedup 1.0000x reference)
//
#include <hip/hip_runtime.h>

typedef unsigned short u16;
typedef __bf16 bf16x8 __attribute__((ext_vector_type(8)));
typedef float f32x4 __attribute__((ext_vector_type(4)));

#define NQ 16384       // queries (8*2048)
#define NC 16384       // codes
#define DD 256         // embed dim
#define BM 256         // block tile M (queries)
#define BN 256         // block tile N (codes)
#define BK 32          // k-step
#define NSPLIT 8
#define NPART (NSPLIT * 2)            // 16: per-(split, wn) partials
#define NTILES ((NC / NSPLIT) / BN)   // 8
#define NSTEPS (NTILES * 8)           // 64 flattened (nt, kc) steps

// ---------- fp32 -> bf16 hi/lo split (RNE) ----------
__device__ __forceinline__ u16 f2bf(float x) {
  unsigned u = __float_as_uint(x);
  u += 0x7fffu + ((u >> 16) & 1u);
  return (u16)(u >> 16);
}
__device__ __forceinline__ float bf2f(u16 h) {
  return __uint_as_float(((unsigned)h) << 16);
}

// async global->LDS, 16B per lane; LDS dest is wave-uniform base + lane*16
__device__ __forceinline__ void gl2lds16(const void* g, void* l) {
  __builtin_amdgcn_global_load_lds((__attribute__((address_space(1))) void*)g,
                                   (__attribute__((address_space(3))) void*)l,
                                   16, 0, 0);
}

// MFMA with accumulator FORCED into AGPRs (proven R3/R6: removes the
// allocator's choice that spilled acc to scratch in R1/R2).
#define MFMA_AGPR(ACC, A, B) \
  asm("v_mfma_f32_16x16x32_bf16 %0, %1, %2, %0" : "+a"(ACC) : "v"(A), "v"(B))

// ---------- K0: split z into bf16 hi/lo ----------
__global__ __launch_bounds__(256) void split_z_kernel(const float* __restrict__ z,
                                                      u16* __restrict__ Ah,
                                                      u16* __restrict__ Al) {
  size_t i = (size_t)blockIdx.x * 256 + threadIdx.x;   // float4 index
  float4 v = ((const float4*)z)[i];
  float f[4] = {v.x, v.y, v.z, v.w};
  u16 hh[4], ll[4];
#pragma unroll
  for (int j = 0; j < 4; ++j) {
    hh[j] = f2bf(f[j]);
    ll[j] = f2bf(f[j] - bf2f(hh[j]));
  }
  ushort4 h; h.x = hh[0]; h.y = hh[1]; h.z = hh[2]; h.w = hh[3];
  ushort4 l; l.x = ll[0]; l.y = ll[1]; l.z = ll[2]; l.w = ll[3];
  ((ushort4*)Ah)[i] = h;
  ((ushort4*)Al)[i] = l;
}

// ---------- K0b: row norms in EXACT numpy pairwise order ----------
__global__ __launch_bounds__(256) void norm256_kernel(const float* __restrict__ x,
                                                      float* __restrict__ nrm) {
  const int t = threadIdx.x;
  const int j = t & 7;                    // accumulator index within row
  const int row = blockIdx.x * 32 + (t >> 3);
  const float* q = x + (size_t)row * 256;
  float half[2];
#pragma unroll
  for (int h = 0; h < 2; ++h) {
    const float* p = q + h * 128;
    float v0 = p[j];
    float r = __fmul_rn(v0, v0);
#pragma unroll
    for (int i = 8; i < 128; i += 8) {
      float v = p[i + j];
      r = __fadd_rn(r, __fmul_rn(v, v));
    }
    float s1 = __fadd_rn(r, __shfl_xor(r, 1));    // r0+r1 | r2+r3 | ...
    float s2 = __fadd_rn(s1, __shfl_xor(s1, 2));  // (r0+r1)+(r2+r3) | ...
    half[h] = __fadd_rn(s2, __shfl_xor(s2, 4));   // full 8-way, np tree order
  }
  if (j == 0) nrm[row] = __fadd_rn(half[0], half[1]);
}

// ---------- K1: qc = cb @ W^T + bias  (fp32, 64x64 tiles) ----------
// DO NOT change numerics here: dist rounding grid depends on qc bits.
__global__ __launch_bounds__(256) void qc_gemm_kernel(const float* __restrict__ cb,
                                                      const float* __restrict__ W,
                                                      const float* __restrict__ bias,
                                                      float* __restrict__ qc) {
  __shared__ float As[64][33];
  __shared__ float Bs[64][33];
  const int bm = blockIdx.x >> 2;   // 256 row tiles
  const int bn = blockIdx.x & 3;    // 4 col tiles
  const int m0 = bm * 64, n0 = bn * 64;
  const int t = threadIdx.x;
  const int tx = t & 15, ty = t >> 4;
  float acc[4][4] = {};
  for (int kc = 0; kc < 256; kc += 32) {
    __syncthreads();
#pragma unroll
    for (int j = 0; j < 8; ++j) {
      int idx = j * 256 + t;            // 0..2047
      int r = idx >> 5, c = idx & 31;
      As[r][c] = cb[(size_t)(m0 + r) * 256 + kc + c];
      Bs[r][c] = W[(size_t)(n0 + r) * 256 + kc + c];
    }
    __syncthreads();
#pragma unroll
    for (int kk = 0; kk < 32; ++kk) {
      float a[4], b[4];
#pragma unroll
      for (int u = 0; u < 4; ++u) a[u] = As[ty * 4 + u][kk];
#pragma unroll
      for (int v = 0; v < 4; ++v) b[v] = Bs[tx * 4 + v][kk];
#pragma unroll
      for (int u = 0; u < 4; ++u)
#pragma unroll
        for (int v = 0; v < 4; ++v) acc[u][v] += a[u] * b[v];
    }
  }
#pragma unroll
  for (int u = 0; u < 4; ++u)
#pragma unroll
    for (int v = 0; v < 4; ++v) {
      int r = m0 + ty * 4 + u, c = n0 + tx * 4 + v;
      qc[(size_t)r * 256 + c] = acc[u][v] + bias[c];
    }
}

// ---------- K1b: per-row bf16 hi/lo split of qc ----------
__global__ __launch_bounds__(256) void split_qc_kernel(const float* __restrict__ qc,
                                                       u16* __restrict__ Bh,
                                                       u16* __restrict__ Bl) {
  size_t i = (size_t)blockIdx.x * 256 + threadIdx.x;   // float4 index
  float4 v = ((const float4*)qc)[i];
  float f[4] = {v.x, v.y, v.z, v.w};
  u16 hh[4], ll[4];
#pragma unroll
  for (int j = 0; j < 4; ++j) {
    hh[j] = f2bf(f[j]);
    ll[j] = f2bf(f[j] - bf2f(hh[j]));
  }
  ushort4 h; h.x = hh[0]; h.y = hh[1]; h.z = hh[2]; h.w = hh[3];
  ushort4 l; l.x = ll[0]; l.y = ll[1]; l.z = ll[2]; l.w = ll[3];
  ((ushort4*)Bh)[i] = h;
  ((ushort4*)Bl)[i] = l;
}

// ---------- K2: fused split-bf16 distance GEMM + argmin ----------
// ROUND 8 STRUCTURE: R6's verified dataflow (256x256 block, 8 waves 4Mx2N,
// 64x128 wave tile, acc[4][8] asm-AGPR, dbuf 128 KB LDS, counted vmcnt:
// B_a -> stage(s+1) -> vmcnt(8) -> B_b -- NEVER 0 in main loop) + the m201
// per-phase rhythm inside the step. R7's pair-lookahead variant HURT
// (sched_barrier caps + serialized lgkm waits); m201's measured-winning
// rhythm instead: per phase {reads issued BEFORE a barrier (in flight during
// rendezvous); barrier; lgkmcnt(0)+sched_barrier (rule 18); setprio(1);
// 24-MFMA cluster; setprio(0); issue next pair's reads (overlap other
// waves' clusters)}. 4 phases/step = 6 barriers/step, each cheap (no vmcnt
// drain ever). Stage addressing rewritten as uniform-base + precomputed
// per-thread 32-bit offsets (same bytes to same places, bit-identical) to
// cut the 64-bit addr VALU burst (VALUBusy 27% measured in R6).
// Numerics: per-acc MFMA order STILL hh->hl->lh over the same ascending
// k-chunks -> bitwise-identical dists and argmin. Epilogue ops, tie-break,
// scan order unchanged. Added barriers separate only reads/MFMAs of the
// same ready buffer (uniform count per wave) -> race-free by construction.
//
// LDS rows are 32 elems = 4 chunks of 16B. XOR swizzle: position p of row r
// holds logical chunk p ^ ((r>>1)&3). Staging permutes the per-lane GLOBAL
// address (global_load_lds dest must stay linear); reads apply the same XOR.
// 8 lanes per 16B-granule = conflict-free (measured 0 in all rounds).

#define READPAIR(P, BH, BL) do { \
    { const int r_ = wn * 128 + ((P) * 2 + 0) * 16 + l15; \
      const int o_ = r_ * BK + rd_sw; \
      (BH)[0] = *(const bf16x8*)&Bhs[cur][o_]; \
      (BL)[0] = *(const bf16x8*)&Bls[cur][o_]; } \
    { const int r_ = wn * 128 + ((P) * 2 + 1) * 16 + l15; \
      const int o_ = r_ * BK + rd_sw; \
      (BH)[1] = *(const bf16x8*)&Bhs[cur][o_]; \
      (BL)[1] = *(const bf16x8*)&Bls[cur][o_]; } \
  } while (0)

#define CLUSTER(PB, BH, BL) do { \
    _Pragma("unroll") for (int u = 0; u < 2; ++u) \
      _Pragma("unroll") for (int mi = 0; mi < 4; ++mi) \
        MFMA_AGPR(acc[mi][(PB) + u], ah[mi], (BH)[u]); \
    _Pragma("unroll") for (int u = 0; u < 2; ++u) \
      _Pragma("unroll") for (int mi = 0; mi < 4; ++mi) \
        MFMA_AGPR(acc[mi][(PB) + u], ah[mi], (BL)[u]); \
    _Pragma("unroll") for (int u = 0; u < 2; ++u) \
      _Pragma("unroll") for (int mi = 0; mi < 4; ++mi) \
        MFMA_AGPR(acc[mi][(PB) + u], al[mi], (BH)[u]); \
  } while (0)

#define PHASE_SYNC() do { \
    __builtin_amdgcn_s_barrier(); \
    asm volatile("s_waitcnt lgkmcnt(0)" ::: "memory"); \
    __builtin_amdgcn_sched_barrier(0); \
  } while (0)

__global__ __launch_bounds__(512, 2) void vq_argmin_kernel(
    const u16* __restrict__ Ah, const u16* __restrict__ Al,
    const u16* __restrict__ Bh, const u16* __restrict__ Bl,
    const float* __restrict__ cnorm, const float* __restrict__ znorm,
    float* __restrict__ pval, int* __restrict__ pidx) {
  __shared__ __align__(16) u16 Ahs[2][BM * BK];   // 2 x 16 KiB
  __shared__ __align__(16) u16 Als[2][BM * BK];   // 2 x 16 KiB
  __shared__ __align__(16) u16 Bhs[2][BN * BK];   // 2 x 16 KiB
  __shared__ __align__(16) u16 Bls[2][BN * BK];   // 2 x 16 KiB  => 128 KiB

  const int bm = blockIdx.x / NSPLIT;
  const int spl = blockIdx.x % NSPLIT;   // == XCD id (blockIdx round-robin)
  const int lane = threadIdx.x & 63;
  const int wid = threadIdx.x >> 6;      // 0..7
  const int wm = wid >> 1, wn = wid & 1; // 4x2 wave grid, 64x128 each
  const int l15 = lane & 15;
  const int lg = lane >> 4;              // 0..3
  const int m0 = bm * BM;
  const int ns0 = spl * (NC / NSPLIT);

  // staging: lane covers (row = sweep*16 + (lane>>2), lds chunk = lane&3);
  // global k-chunk = (lane&3) ^ s(r) with s(r) = (r>>1)&3 = (lane>>3)&3
  const int st_r = lane >> 2;                               // row within 16-row sweep
  const int st_k = (((lane & 3) ^ ((lane >> 3) & 3)) << 3); // SWIZZLED k elem offset

  // read side: logical chunk lg lives at position lg ^ ((l15>>1)&3)
  const int rd_sw = ((lg ^ ((l15 >> 1) & 3)) << 3);         // elem offset within row

  // precomputed per-thread staging offsets (A and B share the same formula;
  // identical bytes->destinations as R6's per-step recompute, VALU-free loop)
  const int grp0 = wid * 2, grp1 = wid * 2 + 1;             // 0..15
  const int stoff0 = (grp0 * 16 + st_r) * DD + st_k;
  const int stoff1 = (grp1 * 16 + st_r) * DD + st_k;
  const int dst0 = grp0 * 512, dst1 = grp1 * 512;           // u16 units

  // stage flattened step s (nt = s>>3, kc = (s&7)*BK): 8 loads/thread.
  auto stage = [&](int buf, int s2) {
    const int kcc = (s2 & 7) * BK;
    const u16* pAh = Ah + (size_t)m0 * DD + kcc;
    const u16* pAl = Al + (size_t)m0 * DD + kcc;
    const size_t bb = (size_t)(ns0 + (s2 >> 3) * BN) * DD + kcc;
    const u16* pBh = Bh + bb;
    const u16* pBl = Bl + bb;
    gl2lds16(pAh + stoff0, &Ahs[buf][dst0]);
    gl2lds16(pAl + stoff0, &Als[buf][dst0]);
    gl2lds16(pBh + stoff0, &Bhs[buf][dst0]);
    gl2lds16(pBl + stoff0, &Bls[buf][dst0]);
    gl2lds16(pAh + stoff1, &Ahs[buf][dst1]);
    gl2lds16(pAl + stoff1, &Als[buf][dst1]);
    gl2lds16(pBh + stoff1, &Bhs[buf][dst1]);
    gl2lds16(pBl + stoff1, &Bls[buf][dst1]);
  };

  float rmin[4][4];
  int ridx[4][4];
#pragma unroll
  for (int a = 0; a < 4; ++a)
#pragma unroll
    for (int b = 0; b < 4; ++b) { rmin[a][b] = 3.4e38f; ridx[a][b] = 0; }

  // prologue: fill buffer 0 with step 0 (only cold drain)
  stage(0, 0);
  asm volatile("s_waitcnt vmcnt(0)" ::: "memory");
  __builtin_amdgcn_s_barrier();

  for (int nt = 0; nt < NTILES; ++nt) {
    const int n0 = ns0 + nt * BN;
    f32x4 acc[4][8];
#pragma unroll
    for (int a = 0; a < 4; ++a)
#pragma unroll
      for (int b = 0; b < 8; ++b) {
        f32x4 zz = {0.f, 0.f, 0.f, 0.f};
        acc[a][b] = zz;
      }

#pragma unroll 1
    for (int k8 = 0; k8 < 8; ++k8) {
      const int s = nt * 8 + k8;
      const int cur = s & 1;

      // B_a: all waves' reads of buf[cur^1] (step s-1) are retired
      __builtin_amdgcn_s_barrier();
      if (s + 1 < NSTEPS) {
        stage(cur ^ 1, s + 1);                           // 8 new loads
        asm volatile("s_waitcnt vmcnt(8)" ::: "memory"); // retire stage(s)
      } else {
        asm volatile("s_waitcnt vmcnt(0)" ::: "memory"); // last step: drain
      }
      // B_b: everyone's stage(s) writes are visible
      __builtin_amdgcn_s_barrier();
      __builtin_amdgcn_sched_barrier(0);

      // issue phase-0 reads: A fragments + B pair 0 (in flight across barrier)
      bf16x8 ah[4], al[4];
#pragma unroll
      for (int mi = 0; mi < 4; ++mi) {
        const int r = wm * 64 + mi * 16 + l15;
        const int off = r * BK + rd_sw;            // swizzled read
        ah[mi] = *(const bf16x8*)&Ahs[cur][off];
        al[mi] = *(const bf16x8*)&Als[cur][off];
      }
      bf16x8 bhA[2], blA[2], bhB[2], blB[2];
      READPAIR(0, bhA, blA);

      // ---- phase 0 ----
      PHASE_SYNC();
      __builtin_amdgcn_s_setprio(1);
      CLUSTER(0, bhA, blA);
      __builtin_amdgcn_s_setprio(0);
      READPAIR(1, bhB, blB);         // overlaps other waves' clusters

      // ---- phase 1 ----
      PHASE_SYNC();
      __builtin_amdgcn_s_setprio(1);
      CLUSTER(2, bhB, blB);
      __builtin_amdgcn_s_setprio(0);
      READPAIR(2, bhA, blA);

      // ---- phase 2 ----
      PHASE_SYNC();
      __builtin_amdgcn_s_setprio(1);
      CLUSTER(4, bhA, blA);
      __builtin_amdgcn_s_setprio(0);
      READPAIR(3, bhB, blB);

      // ---- phase 3 ----
      PHASE_SYNC();
      __builtin_amdgcn_s_setprio(1);
      CLUSTER(6, bhB, blB);
      __builtin_amdgcn_s_setprio(0);
    }

    // epilogue: dist = (zn + cn) - 2*dot, np op order; cols ascending in ni
    // per (mi,i), so tie-break (strict <, first idx wins) is unchanged.
    float cnv[8];
#pragma unroll
    for (int ni = 0; ni < 8; ++ni)
      cnv[ni] = cnorm[n0 + wn * 128 + ni * 16 + l15];
#pragma unroll
    for (int mi = 0; mi < 4; ++mi) {
      float zr[4];
#pragma unroll
      for (int i = 0; i < 4; ++i)
        zr[i] = znorm[m0 + wm * 64 + mi * 16 + lg * 4 + i];
#pragma unroll
      for (int ni = 0; ni < 8; ++ni) {
        const int col = n0 + wn * 128 + ni * 16 + l15;
        const float cn = cnv[ni];
#pragma unroll
        for (int i = 0; i < 4; ++i) {
          const float s = __fadd_rn(zr[i], cn);
          const float v = __fsub_rn(s, __fmul_rn(2.0f, acc[mi][ni][i]));
          if (v < rmin[mi][i]) { rmin[mi][i] = v; ridx[mi][i] = col; }  // strict <
        }
      }
    }
  }
  // 16-lane butterfly reduce (C/D: col=lane&15, row=(lane>>4)*4+i)
#pragma unroll
  for (int mi = 0; mi < 4; ++mi)
#pragma unroll
    for (int i = 0; i < 4; ++i) {
      float v = rmin[mi][i];
      int ix = ridx[mi][i];
#pragma unroll
      for (int d = 1; d < 16; d <<= 1) {
        float ov = __shfl_xor(v, d);
        int oi = __shfl_xor(ix, d);
        if (ov < v || (ov == v && oi < ix)) { v = ov; ix = oi; }
      }
      if (l15 == 0) {
        const int row = m0 + wm * 64 + mi * 16 + lg * 4 + i;
        const int part = spl * 2 + wn;   // per-(split, wn) slot: 0..15
        pval[(size_t)part * NQ + row] = v;
        pidx[(size_t)part * NQ + row] = ix;
      }
    }
}

// ---------- K3: combine partials, gather quantized, loss partial ----------
__global__ __launch_bounds__(256) void finalize_kernel(
    const float* __restrict__ pval, const int* __restrict__ pidx,
    const float* __restrict__ qc, const float* __restrict__ z,
    float* __restrict__ out, float* __restrict__ loss_acc) {
  __shared__ int sidx[8];
  __shared__ float red[256];
  const int bid = blockIdx.x;   // 2048 blocks * 8 rows
  const int t = threadIdx.x;
  if (t < 8) {
    const int row = bid * 8 + t;
    float best = pval[row];
    int bi = pidx[row];
    for (int s2 = 1; s2 < NPART; ++s2) {
      float v = pval[(size_t)s2 * NQ + row];
      int ix = pidx[(size_t)s2 * NQ + row];
      if (v < best || (v == best && ix < bi)) { best = v; bi = ix; }
    }
    sidx[t] = bi;
    out[4194305 + row] = (float)bi;   // encoding_indices as f32
  }
  __syncthreads();
  float d2 = 0.f;
#pragma unroll
  for (int r = 0; r < 8; ++r) {
    const int row = bid * 8 + r;
    const int ix = sidx[r];
    const float q = qc[(size_t)ix * 256 + t];
    const float zz = z[(size_t)row * 256 + t];
    out[(size_t)row * 256 + t] = q;   // STE output == quantized value-wise
    const float d = q - zz;
    d2 += d * d;
  }
  red[t] = d2;
  for (int st = 128; st; st >>= 1) {
    __syncthreads();
    if (t < st) red[t] += red[t + st];
  }
  if (t == 0) atomicAdd(loss_acc, red[0]);
}

// ---------- K4: scalar loss write ----------
__global__ void write_loss_kernel(const float* __restrict__ loss_acc, float* __restrict__ out) {
  // commitment_loss == codebook_loss numerically -> vq_loss = 1.25 * mean
  out[4194304] = 1.25f * loss_acc[0] / 4194304.0f;
}

// ---------- launch ----------
extern "C" void kernel_launch(void* const* d_in, const int* in_sizes, int n_in,
                              void* d_out, int out_size, void* d_ws, size_t ws_size,
                              hipStream_t stream) {
  const float* z = (const float*)d_in[0];
  const float* cb = (const float*)d_in[1];
  const float* W = (const float*)d_in[2];
  const float* bias = (const float*)d_in[3];
  float* out = (float*)d_out;
  char* ws = (char*)d_ws;

  constexpr size_t OFF_QC = 0;                      // 16 MB fp32 quant_codebook
  constexpr size_t OFF_AH = OFF_QC + 16777216;      // 8 MB each
  constexpr size_t OFF_AL = OFF_AH + 8388608;
  constexpr size_t OFF_BH = OFF_AL + 8388608;
  constexpr size_t OFF_BL = OFF_BH + 8388608;
  constexpr size_t OFF_CN = OFF_BL + 8388608;       // 64 KB code norms
  constexpr size_t OFF_ZN = OFF_CN + 65536;         // 64 KB query norms
  constexpr size_t OFF_PV = OFF_ZN + 65536;         // 1 MB partial vals (16 sets)
  constexpr size_t OFF_PI = OFF_PV + 1048576;       // 1 MB partial idx
  constexpr size_t OFF_ACC = OFF_PI + 1048576;      // 4 B loss accumulator

  float* qc = (float*)(ws + OFF_QC);
  u16* Ah = (u16*)(ws + OFF_AH);
  u16* Al = (u16*)(ws + OFF_AL);
  u16* Bh = (u16*)(ws + OFF_BH);
  u16* Bl = (u16*)(ws + OFF_BL);
  float* cn = (float*)(ws + OFF_CN);
  float* zn = (float*)(ws + OFF_ZN);
  float* pv = (float*)(ws + OFF_PV);
  int* pi = (int*)(ws + OFF_PI);
  float* lacc = (float*)(ws + OFF_ACC);

  hipMemsetAsync(lacc, 0, 4, stream);
  split_z_kernel<<<4096, 256, 0, stream>>>(z, Ah, Al);
  qc_gemm_kernel<<<1024, 256, 0, stream>>>(cb, W, bias, qc);
  norm256_kernel<<<NQ / 32, 256, 0, stream>>>(z, zn);
  norm256_kernel<<<NC / 32, 256, 0, stream>>>(qc, cn);
  split_qc_kernel<<<4096, 256, 0, stream>>>(qc, Bh, Bl);
  vq_argmin_kernel<<<(NQ / BM) * NSPLIT, 512, 0, stream>>>(Ah, Al, Bh, Bl, cn, zn, pv, pi);
  finalize_kernel<<<NQ / 8, 256, 0, stream>>>(pv, pi, qc, z, out, lacc);
  write_loss_kernel<<<1, 1, 0, stream>>>(lacc, out);
}

// Round 9
// 522.823 us; speedup vs baseline: 1.0814x; 1.0814x over previous
//
#include <hip/hip_runtime.h>

typedef unsigned short u16;
typedef __bf16 bf16x8 __attribute__((ext_vector_type(8)));
typedef float f32x4 __attribute__((ext_vector_type(4)));

#define NQ 16384       // queries (8*2048)
#define NC 16384       // codes
#define DD 256         // embed dim
#define BM 256         // block tile M (queries)
#define BN 256         // block tile N (codes)
#define BK 32          // k-step
#define NSPLIT 8
#define NPART (NSPLIT * 2)            // 16: per-(split, wn) partials
#define NTILES ((NC / NSPLIT) / BN)   // 8
#define NSTEPS (NTILES * 8)           // 64 flattened (nt, kc) steps

// ---------- fp32 -> bf16 hi/lo split (RNE) ----------
__device__ __forceinline__ u16 f2bf(float x) {
  unsigned u = __float_as_uint(x);
  u += 0x7fffu + ((u >> 16) & 1u);
  return (u16)(u >> 16);
}
__device__ __forceinline__ float bf2f(u16 h) {
  return __uint_as_float(((unsigned)h) << 16);
}

// async global->LDS, 16B per lane; LDS dest is wave-uniform base + lane*16
__device__ __forceinline__ void gl2lds16(const void* g, void* l) {
  __builtin_amdgcn_global_load_lds((__attribute__((address_space(1))) void*)g,
                                   (__attribute__((address_space(3))) void*)l,
                                   16, 0, 0);
}

// MFMA with accumulator FORCED into AGPRs (proven R3/R6: removes the
// allocator's choice that spilled acc to scratch in R1/R2).
#define MFMA_AGPR(ACC, A, B) \
  asm("v_mfma_f32_16x16x32_bf16 %0, %1, %2, %0" : "+a"(ACC) : "v"(A), "v"(B))

// ---------- K0: split z into bf16 hi/lo ----------
__global__ __launch_bounds__(256) void split_z_kernel(const float* __restrict__ z,
                                                      u16* __restrict__ Ah,
                                                      u16* __restrict__ Al) {
  size_t i = (size_t)blockIdx.x * 256 + threadIdx.x;   // float4 index
  float4 v = ((const float4*)z)[i];
  float f[4] = {v.x, v.y, v.z, v.w};
  u16 hh[4], ll[4];
#pragma unroll
  for (int j = 0; j < 4; ++j) {
    hh[j] = f2bf(f[j]);
    ll[j] = f2bf(f[j] - bf2f(hh[j]));
  }
  ushort4 h; h.x = hh[0]; h.y = hh[1]; h.z = hh[2]; h.w = hh[3];
  ushort4 l; l.x = ll[0]; l.y = ll[1]; l.z = ll[2]; l.w = ll[3];
  ((ushort4*)Ah)[i] = h;
  ((ushort4*)Al)[i] = l;
}

// ---------- K0b: row norms in EXACT numpy pairwise order ----------
// Combined kernel: blocks [0, NQ/32) -> z rows into zn; blocks
// [NQ/32, NQ/32+NC/32) -> qc rows into cn. Per-row math is byte-identical
// to the previous two separate launches (np 8-accumulator tree, two
// 128-halves); only the launch count changes.
__global__ __launch_bounds__(256) void norm_both_kernel(const float* __restrict__ z,
                                                        const float* __restrict__ qc,
                                                        float* __restrict__ zn,
                                                        float* __restrict__ cn) {
  const int t = threadIdx.x;
  const int j = t & 7;                    // accumulator index within row
  const bool isq = blockIdx.x >= (NQ / 32);
  const int b = isq ? (blockIdx.x - NQ / 32) : blockIdx.x;
  const float* x = isq ? qc : z;
  float* nrm = isq ? cn : zn;
  const int row = b * 32 + (t >> 3);
  const float* q = x + (size_t)row * 256;
  float half[2];
#pragma unroll
  for (int h = 0; h < 2; ++h) {
    const float* p = q + h * 128;
    float v0 = p[j];
    float r = __fmul_rn(v0, v0);
#pragma unroll
    for (int i = 8; i < 128; i += 8) {
      float v = p[i + j];
      r = __fadd_rn(r, __fmul_rn(v, v));
    }
    float s1 = __fadd_rn(r, __shfl_xor(r, 1));    // r0+r1 | r2+r3 | ...
    float s2 = __fadd_rn(s1, __shfl_xor(s1, 2));  // (r0+r1)+(r2+r3) | ...
    half[h] = __fadd_rn(s2, __shfl_xor(s2, 4));   // full 8-way, np tree order
  }
  if (j == 0) nrm[row] = __fadd_rn(half[0], half[1]);
}

// ---------- K1: qc = cb @ W^T + bias, FUSED with per-row bf16 hi/lo split ---
// DO NOT change the GEMM numerics: dist rounding grid depends on qc bits.
// The fusion applies the identical f2bf hi/lo split (previously a separate
// split_qc dispatch) to the SAME in-register fp32 value acc+bias -> the
// bytes written to qc, Bh, Bl are bit-identical to the unfused pipeline;
// one 16MB-read + 16MB-write round trip and one launch are eliminated.
__global__ __launch_bounds__(256) void qc_gemm_kernel(const float* __restrict__ cb,
                                                      const float* __restrict__ W,
                                                      const float* __restrict__ bias,
                                                      float* __restrict__ qc,
                                                      u16* __restrict__ Bh,
                                                      u16* __restrict__ Bl) {
  __shared__ float As[64][33];
  __shared__ float Bs[64][33];
  const int bm = blockIdx.x >> 2;   // 256 row tiles
  const int bn = blockIdx.x & 3;    // 4 col tiles
  const int m0 = bm * 64, n0 = bn * 64;
  const int t = threadIdx.x;
  const int tx = t & 15, ty = t >> 4;
  float acc[4][4] = {};
  for (int kc = 0; kc < 256; kc += 32) {
    __syncthreads();
#pragma unroll
    for (int j = 0; j < 8; ++j) {
      int idx = j * 256 + t;            // 0..2047
      int r = idx >> 5, c = idx & 31;
      As[r][c] = cb[(size_t)(m0 + r) * 256 + kc + c];
      Bs[r][c] = W[(size_t)(n0 + r) * 256 + kc + c];
    }
    __syncthreads();
#pragma unroll
    for (int kk = 0; kk < 32; ++kk) {
      float a[4], b[4];
#pragma unroll
      for (int u = 0; u < 4; ++u) a[u] = As[ty * 4 + u][kk];
#pragma unroll
      for (int v = 0; v < 4; ++v) b[v] = Bs[tx * 4 + v][kk];
#pragma unroll
      for (int u = 0; u < 4; ++u)
#pragma unroll
        for (int v = 0; v < 4; ++v) acc[u][v] += a[u] * b[v];
    }
  }
#pragma unroll
  for (int u = 0; u < 4; ++u) {
    const int r = m0 + ty * 4 + u;
    const int c0 = n0 + tx * 4;
    float q4[4];
#pragma unroll
    for (int v = 0; v < 4; ++v) q4[v] = acc[u][v] + bias[c0 + v];
    float4 qv; qv.x = q4[0]; qv.y = q4[1]; qv.z = q4[2]; qv.w = q4[3];
    *(float4*)&qc[(size_t)r * 256 + c0] = qv;
    u16 hh[4], ll[4];
#pragma unroll
    for (int v = 0; v < 4; ++v) {
      hh[v] = f2bf(q4[v]);
      ll[v] = f2bf(q4[v] - bf2f(hh[v]));
    }
    ushort4 h; h.x = hh[0]; h.y = hh[1]; h.z = hh[2]; h.w = hh[3];
    ushort4 l; l.x = ll[0]; l.y = ll[1]; l.z = ll[2]; l.w = ll[3];
    *(ushort4*)&Bh[(size_t)r * 256 + c0] = h;
    *(ushort4*)&Bl[(size_t)r * 256 + c0] = l;
  }
}

// ---------- K2: fused split-bf16 distance GEMM + argmin ----------
// ROUND 9: revert to the R6 structure VERBATIM (best measured: 406 us,
// MfmaUtil 46%, zero spill, zero conflicts) -- four schedule variants
// (R0/R6/R7/R8) clustered at 42-50%, R6 fastest; further phase-rhythm
// grafts measured negative (guide m196: coarse splits hurt). Only change
// vs R6: R8's precomputed per-thread staging offsets (HW-verified in R8,
// byte-identical staging) to trim the 64-bit addr VALU burst.
// Structure: 256x256 block (512 thr, 8 waves 4Mx2N), 64x128 wave tile,
// acc[4][8] asm-AGPR, dbuf 128 KB LDS, counted vmcnt (never 0 in main
// loop): B_a -> stage(s+1) -> vmcnt(8) -> B_b; quad-split B frags with
// sched_barrier; setprio around MFMA block.
// Numerics: per-acc MFMA order hh->hl->lh over ascending k-chunks ->
// bitwise-identical dists and argmin. Epilogue ops, tie-break unchanged.
//
// LDS rows are 32 elems = 4 chunks of 16B. XOR swizzle: position p of row r
// holds logical chunk p ^ ((r>>1)&3). Staging permutes the per-lane GLOBAL
// address (global_load_lds dest must stay linear); reads apply the same XOR.
// 8 lanes per 16B-granule = conflict-free (measured 0 in all rounds).
__global__ __launch_bounds__(512, 2) void vq_argmin_kernel(
    const u16* __restrict__ Ah, const u16* __restrict__ Al,
    const u16* __restrict__ Bh, const u16* __restrict__ Bl,
    const float* __restrict__ cnorm, const float* __restrict__ znorm,
    float* __restrict__ pval, int* __restrict__ pidx) {
  __shared__ __align__(16) u16 Ahs[2][BM * BK];   // 2 x 16 KiB
  __shared__ __align__(16) u16 Als[2][BM * BK];   // 2 x 16 KiB
  __shared__ __align__(16) u16 Bhs[2][BN * BK];   // 2 x 16 KiB
  __shared__ __align__(16) u16 Bls[2][BN * BK];   // 2 x 16 KiB  => 128 KiB

  const int bm = blockIdx.x / NSPLIT;
  const int spl = blockIdx.x % NSPLIT;   // == XCD id (blockIdx round-robin)
  const int lane = threadIdx.x & 63;
  const int wid = threadIdx.x >> 6;      // 0..7
  const int wm = wid >> 1, wn = wid & 1; // 4x2 wave grid, 64x128 each
  const int l15 = lane & 15;
  const int lg = lane >> 4;              // 0..3
  const int m0 = bm * BM;
  const int ns0 = spl * (NC / NSPLIT);

  // staging: lane covers (row = sweep*16 + (lane>>2), lds chunk = lane&3);
  // global k-chunk = (lane&3) ^ s(r) with s(r) = (r>>1)&3 = (lane>>3)&3
  const int st_r = lane >> 2;                               // row within 16-row sweep
  const int st_k = (((lane & 3) ^ ((lane >> 3) & 3)) << 3); // SWIZZLED k elem offset

  // read side: logical chunk lg lives at position lg ^ ((l15>>1)&3)
  const int rd_sw = ((lg ^ ((l15 >> 1) & 3)) << 3);         // elem offset within row

  // precomputed per-thread staging offsets (identical bytes->destinations
  // as the per-step recompute; VALU-free inner loop) [R8-verified]
  const int grp0 = wid * 2, grp1 = wid * 2 + 1;             // 0..15
  const int stoff0 = (grp0 * 16 + st_r) * DD + st_k;
  const int stoff1 = (grp1 * 16 + st_r) * DD + st_k;
  const int dst0 = grp0 * 512, dst1 = grp1 * 512;           // u16 units

  // stage flattened step s (nt = s>>3, kc = (s&7)*BK): 8 loads/thread.
  auto stage = [&](int buf, int s2) {
    const int kcc = (s2 & 7) * BK;
    const u16* pAh = Ah + (size_t)m0 * DD + kcc;
    const u16* pAl = Al + (size_t)m0 * DD + kcc;
    const size_t bb = (size_t)(ns0 + (s2 >> 3) * BN) * DD + kcc;
    const u16* pBh = Bh + bb;
    const u16* pBl = Bl + bb;
    gl2lds16(pAh + stoff0, &Ahs[buf][dst0]);
    gl2lds16(pAl + stoff0, &Als[buf][dst0]);
    gl2lds16(pBh + stoff0, &Bhs[buf][dst0]);
    gl2lds16(pBl + stoff0, &Bls[buf][dst0]);
    gl2lds16(pAh + stoff1, &Ahs[buf][dst1]);
    gl2lds16(pAl + stoff1, &Als[buf][dst1]);
    gl2lds16(pBh + stoff1, &Bhs[buf][dst1]);
    gl2lds16(pBl + stoff1, &Bls[buf][dst1]);
  };

  float rmin[4][4];
  int ridx[4][4];
#pragma unroll
  for (int a = 0; a < 4; ++a)
#pragma unroll
    for (int b = 0; b < 4; ++b) { rmin[a][b] = 3.4e38f; ridx[a][b] = 0; }

  // prologue: fill buffer 0 with step 0 (only place vmcnt hits 0 cold)
  stage(0, 0);
  asm volatile("s_waitcnt vmcnt(0)" ::: "memory");
  __builtin_amdgcn_s_barrier();

  for (int nt = 0; nt < NTILES; ++nt) {
    const int n0 = ns0 + nt * BN;
    f32x4 acc[4][8];
#pragma unroll
    for (int a = 0; a < 4; ++a)
#pragma unroll
      for (int b = 0; b < 8; ++b) {
        f32x4 zz = {0.f, 0.f, 0.f, 0.f};
        acc[a][b] = zz;
      }

#pragma unroll 1
    for (int k8 = 0; k8 < 8; ++k8) {
      const int s = nt * 8 + k8;
      const int cur = s & 1;

      // B_a: all waves' reads of buf[cur^1] (step s-1) are retired
      __builtin_amdgcn_s_barrier();
      if (s + 1 < NSTEPS) {
        stage(cur ^ 1, s + 1);                           // 8 new loads
        asm volatile("s_waitcnt vmcnt(8)" ::: "memory"); // retire stage(s)
      } else {
        asm volatile("s_waitcnt vmcnt(0)" ::: "memory"); // last step: drain
      }
      // B_b: everyone's stage(s) writes are visible
      __builtin_amdgcn_s_barrier();
      __builtin_amdgcn_sched_barrier(0);

      bf16x8 ah[4], al[4];
#pragma unroll
      for (int mi = 0; mi < 4; ++mi) {
        const int r = wm * 64 + mi * 16 + l15;
        const int off = r * BK + rd_sw;            // swizzled read
        ah[mi] = *(const bf16x8*)&Ahs[cur][off];
        al[mi] = *(const bf16x8*)&Als[cur][off];
      }
      __builtin_amdgcn_s_setprio(1);
      // ---- quad 0: ni = 0..3 (B frags capped at 32 VGPRs live) ----
      {
        bf16x8 bh[4], bl[4];
#pragma unroll
        for (int nq = 0; nq < 4; ++nq) {
          const int r = wn * 128 + nq * 16 + l15;
          const int off = r * BK + rd_sw;          // swizzled read
          bh[nq] = *(const bf16x8*)&Bhs[cur][off];
          bl[nq] = *(const bf16x8*)&Bls[cur][off];
        }
        // 3 passes; per-acc order hh -> hl -> lh (bitwise-identical)
#pragma unroll
        for (int nq = 0; nq < 4; ++nq)
#pragma unroll
          for (int mi = 0; mi < 4; ++mi)
            MFMA_AGPR(acc[mi][nq], ah[mi], bh[nq]);
#pragma unroll
        for (int nq = 0; nq < 4; ++nq)
#pragma unroll
          for (int mi = 0; mi < 4; ++mi)
            MFMA_AGPR(acc[mi][nq], ah[mi], bl[nq]);
#pragma unroll
        for (int nq = 0; nq < 4; ++nq)
#pragma unroll
          for (int mi = 0; mi < 4; ++mi)
            MFMA_AGPR(acc[mi][nq], al[mi], bh[nq]);
      }
      __builtin_amdgcn_sched_barrier(0);  // do NOT hoist quad-1 B loads
      // ---- quad 1: ni = 4..7 ----
      {
        bf16x8 bh[4], bl[4];
#pragma unroll
        for (int nq = 0; nq < 4; ++nq) {
          const int r = wn * 128 + (4 + nq) * 16 + l15;
          const int off = r * BK + rd_sw;          // swizzled read
          bh[nq] = *(const bf16x8*)&Bhs[cur][off];
          bl[nq] = *(const bf16x8*)&Bls[cur][off];
        }
#pragma unroll
        for (int nq = 0; nq < 4; ++nq)
#pragma unroll
          for (int mi = 0; mi < 4; ++mi)
            MFMA_AGPR(acc[mi][4 + nq], ah[mi], bh[nq]);
#pragma unroll
        for (int nq = 0; nq < 4; ++nq)
#pragma unroll
          for (int mi = 0; mi < 4; ++mi)
            MFMA_AGPR(acc[mi][4 + nq], ah[mi], bl[nq]);
#pragma unroll
        for (int nq = 0; nq < 4; ++nq)
#pragma unroll
          for (int mi = 0; mi < 4; ++mi)
            MFMA_AGPR(acc[mi][4 + nq], al[mi], bh[nq]);
      }
      __builtin_amdgcn_s_setprio(0);
    }

    // epilogue: dist = (zn + cn) - 2*dot, np op order; cols ascending in ni
    // per (mi,i), so tie-break (strict <, first idx wins) is unchanged.
    float cnv[8];
#pragma unroll
    for (int ni = 0; ni < 8; ++ni)
      cnv[ni] = cnorm[n0 + wn * 128 + ni * 16 + l15];
#pragma unroll
    for (int mi = 0; mi < 4; ++mi) {
      float zr[4];
#pragma unroll
      for (int i = 0; i < 4; ++i)
        zr[i] = znorm[m0 + wm * 64 + mi * 16 + lg * 4 + i];
#pragma unroll
      for (int ni = 0; ni < 8; ++ni) {
        const int col = n0 + wn * 128 + ni * 16 + l15;
        const float cn = cnv[ni];
#pragma unroll
        for (int i = 0; i < 4; ++i) {
          const float s = __fadd_rn(zr[i], cn);
          const float v = __fsub_rn(s, __fmul_rn(2.0f, acc[mi][ni][i]));
          if (v < rmin[mi][i]) { rmin[mi][i] = v; ridx[mi][i] = col; }  // strict <
        }
      }
    }
  }
  // 16-lane butterfly reduce (C/D: col=lane&15, row=(lane>>4)*4+i)
#pragma unroll
  for (int mi = 0; mi < 4; ++mi)
#pragma unroll
    for (int i = 0; i < 4; ++i) {
      float v = rmin[mi][i];
      int ix = ridx[mi][i];
#pragma unroll
      for (int d = 1; d < 16; d <<= 1) {
        float ov = __shfl_xor(v, d);
        int oi = __shfl_xor(ix, d);
        if (ov < v || (ov == v && oi < ix)) { v = ov; ix = oi; }
      }
      if (l15 == 0) {
        const int row = m0 + wm * 64 + mi * 16 + lg * 4 + i;
        const int part = spl * 2 + wn;   // per-(split, wn) slot: 0..15
        pval[(size_t)part * NQ + row] = v;
        pidx[(size_t)part * NQ + row] = ix;
      }
    }
}

// ---------- K3: combine partials, gather quantized, loss partial ----------
__global__ __launch_bounds__(256) void finalize_kernel(
    const float* __restrict__ pval, const int* __restrict__ pidx,
    const float* __restrict__ qc, const float* __restrict__ z,
    float* __restrict__ out, float* __restrict__ loss_acc) {
  __shared__ int sidx[8];
  __shared__ float red[256];
  const int bid = blockIdx.x;   // 2048 blocks * 8 rows
  const int t = threadIdx.x;
  if (t < 8) {
    const int row = bid * 8 + t;
    float best = pval[row];
    int bi = pidx[row];
    for (int s2 = 1; s2 < NPART; ++s2) {
      float v = pval[(size_t)s2 * NQ + row];
      int ix = pidx[(size_t)s2 * NQ + row];
      if (v < best || (v == best && ix < bi)) { best = v; bi = ix; }
    }
    sidx[t] = bi;
    out[4194305 + row] = (float)bi;   // encoding_indices as f32
  }
  __syncthreads();
  float d2 = 0.f;
#pragma unroll
  for (int r = 0; r < 8; ++r) {
    const int row = bid * 8 + r;
    const int ix = sidx[r];
    const float q = qc[(size_t)ix * 256 + t];
    const float zz = z[(size_t)row * 256 + t];
    out[(size_t)row * 256 + t] = q;   // STE output == quantized value-wise
    const float d = q - zz;
    d2 += d * d;
  }
  red[t] = d2;
  for (int st = 128; st; st >>= 1) {
    __syncthreads();
    if (t < st) red[t] += red[t + st];
  }
  if (t == 0) atomicAdd(loss_acc, red[0]);
}

// ---------- K4: scalar loss write ----------
__global__ void write_loss_kernel(const float* __restrict__ loss_acc, float* __restrict__ out) {
  // commitment_loss == codebook_loss numerically -> vq_loss = 1.25 * mean
  out[4194304] = 1.25f * loss_acc[0] / 4194304.0f;
}

// ---------- launch ----------
extern "C" void kernel_launch(void* const* d_in, const int* in_sizes, int n_in,
                              void* d_out, int out_size, void* d_ws, size_t ws_size,
                              hipStream_t stream) {
  const float* z = (const float*)d_in[0];
  const float* cb = (const float*)d_in[1];
  const float* W = (const float*)d_in[2];
  const float* bias = (const float*)d_in[3];
  float* out = (float*)d_out;
  char* ws = (char*)d_ws;

  constexpr size_t OFF_QC = 0;                      // 16 MB fp32 quant_codebook
  constexpr size_t OFF_AH = OFF_QC + 16777216;      // 8 MB each
  constexpr size_t OFF_AL = OFF_AH + 8388608;
  constexpr size_t OFF_BH = OFF_AL + 8388608;
  constexpr size_t OFF_BL = OFF_BH + 8388608;
  constexpr size_t OFF_CN = OFF_BL + 8388608;       // 64 KB code norms
  constexpr size_t OFF_ZN = OFF_CN + 65536;         // 64 KB query norms
  constexpr size_t OFF_PV = OFF_ZN + 65536;         // 1 MB partial vals (16 sets)
  constexpr size_t OFF_PI = OFF_PV + 1048576;       // 1 MB partial idx
  constexpr size_t OFF_ACC = OFF_PI + 1048576;      // 4 B loss accumulator

  float* qc = (float*)(ws + OFF_QC);
  u16* Ah = (u16*)(ws + OFF_AH);
  u16* Al = (u16*)(ws + OFF_AL);
  u16* Bh = (u16*)(ws + OFF_BH);
  u16* Bl = (u16*)(ws + OFF_BL);
  float* cn = (float*)(ws + OFF_CN);
  float* zn = (float*)(ws + OFF_ZN);
  float* pv = (float*)(ws + OFF_PV);
  int* pi = (int*)(ws + OFF_PI);
  float* lacc = (float*)(ws + OFF_ACC);

  hipMemsetAsync(lacc, 0, 4, stream);
  split_z_kernel<<<4096, 256, 0, stream>>>(z, Ah, Al);
  qc_gemm_kernel<<<1024, 256, 0, stream>>>(cb, W, bias, qc, Bh, Bl);
  norm_both_kernel<<<NQ / 32 + NC / 32, 256, 0, stream>>>(z, qc, zn, cn);
  vq_argmin_kernel<<<(NQ / BM) * NSPLIT, 512, 0, stream>>>(Ah, Al, Bh, Bl, cn, zn, pv, pi);
  finalize_kernel<<<NQ / 8, 256, 0, stream>>>(pv, pi, qc, z, out, lacc);
  write_loss_kernel<<<1, 1, 0, stream>>>(lacc, out);
}

// Round 10
// 507.846 us; speedup vs baseline: 1.1133x; 1.0295x over previous
//
#include <hip/hip_runtime.h>

typedef unsigned short u16;
typedef __bf16 bf16x8 __attribute__((ext_vector_type(8)));
typedef float f32x4 __attribute__((ext_vector_type(4)));

#define NQ 16384       // queries (8*2048)
#define NC 16384       // codes
#define DD 256         // embed dim
#define BM 256         // block tile M (queries)
#define BN 256         // block tile N (codes)
#define BK 32          // k-step
#define NSPLIT 8
#define NPART (NSPLIT * 2)            // 16: per-(split, wn) partials
#define NTILES ((NC / NSPLIT) / BN)   // 8
#define NSTEPS (NTILES * 8)           // 64 flattened (nt, kc) steps

// ---------- fp32 -> bf16 hi/lo split (RNE) ----------
__device__ __forceinline__ u16 f2bf(float x) {
  unsigned u = __float_as_uint(x);
  u += 0x7fffu + ((u >> 16) & 1u);
  return (u16)(u >> 16);
}
__device__ __forceinline__ float bf2f(u16 h) {
  return __uint_as_float(((unsigned)h) << 16);
}

// async global->LDS, 16B per lane; LDS dest is wave-uniform base + lane*16
__device__ __forceinline__ void gl2lds16(const void* g, void* l) {
  __builtin_amdgcn_global_load_lds((__attribute__((address_space(1))) void*)g,
                                   (__attribute__((address_space(3))) void*)l,
                                   16, 0, 0);
}

// MFMA with accumulator FORCED into AGPRs (proven R3/R6: removes the
// allocator's choice that spilled acc to scratch in R1/R2).
#define MFMA_AGPR(ACC, A, B) \
  asm("v_mfma_f32_16x16x32_bf16 %0, %1, %2, %0" : "+a"(ACC) : "v"(A), "v"(B))

// ---------- K0: split z into bf16 hi/lo, FUSED with z row norms ----------
// Phase 1: identical float4 split mapping as the old split_z (i ->
// ((ushort4*)Ah)[i] unchanged -> Ah/Al bytes identical); the raw z float4s
// are also parked in LDS (32 rows/block).
// Phase 2: the EXACT norm256 math (np 8-accumulator tree over two 128-
// halves, same shfl_xor combine order, same thread mapping) sourced from
// LDS instead of a second global read -> zn bits identical.
__global__ __launch_bounds__(256) void split_z_norm_kernel(const float* __restrict__ z,
                                                           u16* __restrict__ Ah,
                                                           u16* __restrict__ Al,
                                                           float* __restrict__ zn) {
  __shared__ float zs[32 * 256];   // 32 KiB: this block's 32 rows
  const int t = threadIdx.x;
#pragma unroll
  for (int j = 0; j < 8; ++j) {
    const int loc = j * 256 + t;                       // local float4 idx 0..2047
    const size_t i = (size_t)blockIdx.x * 2048 + loc;  // global float4 idx
    float4 v = ((const float4*)z)[i];
    *(float4*)&zs[loc * 4] = v;
    float f[4] = {v.x, v.y, v.z, v.w};
    u16 hh[4], ll[4];
#pragma unroll
    for (int q = 0; q < 4; ++q) {
      hh[q] = f2bf(f[q]);
      ll[q] = f2bf(f[q] - bf2f(hh[q]));
    }
    ushort4 h; h.x = hh[0]; h.y = hh[1]; h.z = hh[2]; h.w = hh[3];
    ushort4 l; l.x = ll[0]; l.y = ll[1]; l.z = ll[2]; l.w = ll[3];
    ((ushort4*)Ah)[i] = h;
    ((ushort4*)Al)[i] = l;
  }
  __syncthreads();
  // phase 2: norm in EXACT numpy pairwise order (identical to norm256)
  const int j = t & 7;
  const int lrow = t >> 3;
  const int row = blockIdx.x * 32 + lrow;
  const float* q = zs + lrow * 256;
  float half[2];
#pragma unroll
  for (int h = 0; h < 2; ++h) {
    const float* p = q + h * 128;
    float v0 = p[j];
    float r = __fmul_rn(v0, v0);
#pragma unroll
    for (int i = 8; i < 128; i += 8) {
      float v = p[i + j];
      r = __fadd_rn(r, __fmul_rn(v, v));
    }
    float s1 = __fadd_rn(r, __shfl_xor(r, 1));
    float s2 = __fadd_rn(s1, __shfl_xor(s1, 2));
    half[h] = __fadd_rn(s2, __shfl_xor(s2, 4));
  }
  if (j == 0) zn[row] = __fadd_rn(half[0], half[1]);
}

// ---------- K0b: qc row norms in EXACT numpy pairwise order ----------
__global__ __launch_bounds__(256) void norm256_kernel(const float* __restrict__ x,
                                                      float* __restrict__ nrm) {
  const int t = threadIdx.x;
  const int j = t & 7;                    // accumulator index within row
  const int row = blockIdx.x * 32 + (t >> 3);
  const float* q = x + (size_t)row * 256;
  float half[2];
#pragma unroll
  for (int h = 0; h < 2; ++h) {
    const float* p = q + h * 128;
    float v0 = p[j];
    float r = __fmul_rn(v0, v0);
#pragma unroll
    for (int i = 8; i < 128; i += 8) {
      float v = p[i + j];
      r = __fadd_rn(r, __fmul_rn(v, v));
    }
    float s1 = __fadd_rn(r, __shfl_xor(r, 1));    // r0+r1 | r2+r3 | ...
    float s2 = __fadd_rn(s1, __shfl_xor(s1, 2));  // (r0+r1)+(r2+r3) | ...
    half[h] = __fadd_rn(s2, __shfl_xor(s2, 4));   // full 8-way, np tree order
  }
  if (j == 0) nrm[row] = __fadd_rn(half[0], half[1]);
}

// ---------- K1: qc = cb @ W^T + bias, fused bf16 hi/lo split (v2) ----------
// ROUND 10 REWRITE. The old 64x64/scalar-LDS version was LDS-issue-bound:
// 8 ds_read_b32 per 16 FMAs -> ~190K cyc/CU ~= 79 us (it was ~63% of the
// non-vq time). v2: 128x128 tiles (grid 256 = 1/CU), 8x8 per thread, LDS
// stored TRANSPOSED [kk][r] (pad 132 keeps float4 16B-aligned; write banks
// spread 4c+r) so fragments load as float4: 4 ds_read_b128 per 64 FMAs.
// NUMERICS: each output's fp32 FMA chain is over k ASCENDING (kc blocks,
// kk ascending) -- identical per-output order to the old kernel, so qc
// bits are unchanged (tile geometry doesn't enter the chain). Bias add and
// the fused f2bf hi/lo split are the same ops on the same values -> qc,
// Bh, Bl bytes all bit-identical to R9.
__global__ __launch_bounds__(256) void qc_gemm_kernel(const float* __restrict__ cb,
                                                      const float* __restrict__ W,
                                                      const float* __restrict__ bias,
                                                      float* __restrict__ qc,
                                                      u16* __restrict__ Bh,
                                                      u16* __restrict__ Bl) {
  __shared__ float At[32][132];   // [kk][r], pad->16B-aligned rows
  __shared__ float Bt[32][132];
  const int bm = blockIdx.x >> 1;   // 128 row tiles
  const int bn = blockIdx.x & 1;    // 2 col tiles
  const int m0 = bm * 128, n0 = bn * 128;
  const int t = threadIdx.x;
  const int tx = t & 15, ty = t >> 4;   // 16x16 threads, 8x8 each
  float acc[8][8] = {};
  for (int kc = 0; kc < 256; kc += 32) {
    __syncthreads();
    // stage 128 rows x 32 k, transposed: At[c][r] = cb[m0+r][kc+c]
#pragma unroll
    for (int j = 0; j < 16; ++j) {
      const int idx = j * 256 + t;        // 0..4095
      const int r = idx >> 5, c = idx & 31;
      At[c][r] = cb[(size_t)(m0 + r) * 256 + kc + c];
      Bt[c][r] = W[(size_t)(n0 + r) * 256 + kc + c];
    }
    __syncthreads();
#pragma unroll
    for (int kk = 0; kk < 32; ++kk) {
      float4 a0 = *(const float4*)&At[kk][ty * 8];
      float4 a1 = *(const float4*)&At[kk][ty * 8 + 4];
      float4 b0 = *(const float4*)&Bt[kk][tx * 8];
      float4 b1 = *(const float4*)&Bt[kk][tx * 8 + 4];
      float a[8] = {a0.x, a0.y, a0.z, a0.w, a1.x, a1.y, a1.z, a1.w};
      float b[8] = {b0.x, b0.y, b0.z, b0.w, b1.x, b1.y, b1.z, b1.w};
#pragma unroll
      for (int u = 0; u < 8; ++u)
#pragma unroll
        for (int v = 0; v < 8; ++v) acc[u][v] += a[u] * b[v];
    }
  }
  // epilogue: +bias, store qc fp32, fused hi/lo split (same ops as R9)
#pragma unroll
  for (int u = 0; u < 8; ++u) {
    const int r = m0 + ty * 8 + u;
#pragma unroll
    for (int g = 0; g < 2; ++g) {
      const int c0 = n0 + tx * 8 + g * 4;
      float q4[4];
#pragma unroll
      for (int v = 0; v < 4; ++v) q4[v] = acc[u][g * 4 + v] + bias[c0 + v];
      float4 qv; qv.x = q4[0]; qv.y = q4[1]; qv.z = q4[2]; qv.w = q4[3];
      *(float4*)&qc[(size_t)r * 256 + c0] = qv;
      u16 hh[4], ll[4];
#pragma unroll
      for (int v = 0; v < 4; ++v) {
        hh[v] = f2bf(q4[v]);
        ll[v] = f2bf(q4[v] - bf2f(hh[v]));
      }
      ushort4 h; h.x = hh[0]; h.y = hh[1]; h.z = hh[2]; h.w = hh[3];
      ushort4 l; l.x = ll[0]; l.y = ll[1]; l.z = ll[2]; l.w = ll[3];
      *(ushort4*)&Bh[(size_t)r * 256 + c0] = h;
      *(ushort4*)&Bl[(size_t)r * 256 + c0] = l;
    }
  }
}

// ---------- K2: fused split-bf16 distance GEMM + argmin ----------
// R9-VERBATIM (measured best: 402 us, MfmaUtil 46%, zero spill, zero
// conflicts). Four schedule variants (R0/R6/R7/R8) clustered at 42-50%;
// phase-rhythm grafts measured negative -> this is the plain-HIP plateau
// for this op. Structure: 256x256 block (512 thr, 8 waves 4Mx2N), 64x128
// wave tile, acc[4][8] asm-AGPR, dbuf 128 KB LDS, counted vmcnt (never 0
// in main loop): B_a -> stage(s+1) -> vmcnt(8) -> B_b; quad-split B frags;
// setprio around MFMA block; precomputed staging offsets.
// Numerics: per-acc MFMA order hh->hl->lh over ascending k-chunks ->
// bitwise-identical dists and argmin. Epilogue ops, tie-break unchanged.
__global__ __launch_bounds__(512, 2) void vq_argmin_kernel(
    const u16* __restrict__ Ah, const u16* __restrict__ Al,
    const u16* __restrict__ Bh, const u16* __restrict__ Bl,
    const float* __restrict__ cnorm, const float* __restrict__ znorm,
    float* __restrict__ pval, int* __restrict__ pidx) {
  __shared__ __align__(16) u16 Ahs[2][BM * BK];   // 2 x 16 KiB
  __shared__ __align__(16) u16 Als[2][BM * BK];   // 2 x 16 KiB
  __shared__ __align__(16) u16 Bhs[2][BN * BK];   // 2 x 16 KiB
  __shared__ __align__(16) u16 Bls[2][BN * BK];   // 2 x 16 KiB  => 128 KiB

  const int bm = blockIdx.x / NSPLIT;
  const int spl = blockIdx.x % NSPLIT;   // == XCD id (blockIdx round-robin)
  const int lane = threadIdx.x & 63;
  const int wid = threadIdx.x >> 6;      // 0..7
  const int wm = wid >> 1, wn = wid & 1; // 4x2 wave grid, 64x128 each
  const int l15 = lane & 15;
  const int lg = lane >> 4;              // 0..3
  const int m0 = bm * BM;
  const int ns0 = spl * (NC / NSPLIT);

  // staging: lane covers (row = sweep*16 + (lane>>2), lds chunk = lane&3);
  // global k-chunk = (lane&3) ^ s(r) with s(r) = (r>>1)&3 = (lane>>3)&3
  const int st_r = lane >> 2;                               // row within 16-row sweep
  const int st_k = (((lane & 3) ^ ((lane >> 3) & 3)) << 3); // SWIZZLED k elem offset

  // read side: logical chunk lg lives at position lg ^ ((l15>>1)&3)
  const int rd_sw = ((lg ^ ((l15 >> 1) & 3)) << 3);         // elem offset within row

  // precomputed per-thread staging offsets (identical bytes->destinations
  // as the per-step recompute; VALU-free inner loop) [R8-verified]
  const int grp0 = wid * 2, grp1 = wid * 2 + 1;             // 0..15
  const int stoff0 = (grp0 * 16 + st_r) * DD + st_k;
  const int stoff1 = (grp1 * 16 + st_r) * DD + st_k;
  const int dst0 = grp0 * 512, dst1 = grp1 * 512;           // u16 units

  // stage flattened step s (nt = s>>3, kc = (s&7)*BK): 8 loads/thread.
  auto stage = [&](int buf, int s2) {
    const int kcc = (s2 & 7) * BK;
    const u16* pAh = Ah + (size_t)m0 * DD + kcc;
    const u16* pAl = Al + (size_t)m0 * DD + kcc;
    const size_t bb = (size_t)(ns0 + (s2 >> 3) * BN) * DD + kcc;
    const u16* pBh = Bh + bb;
    const u16* pBl = Bl + bb;
    gl2lds16(pAh + stoff0, &Ahs[buf][dst0]);
    gl2lds16(pAl + stoff0, &Als[buf][dst0]);
    gl2lds16(pBh + stoff0, &Bhs[buf][dst0]);
    gl2lds16(pBl + stoff0, &Bls[buf][dst0]);
    gl2lds16(pAh + stoff1, &Ahs[buf][dst1]);
    gl2lds16(pAl + stoff1, &Als[buf][dst1]);
    gl2lds16(pBh + stoff1, &Bhs[buf][dst1]);
    gl2lds16(pBl + stoff1, &Bls[buf][dst1]);
  };

  float rmin[4][4];
  int ridx[4][4];
#pragma unroll
  for (int a = 0; a < 4; ++a)
#pragma unroll
    for (int b = 0; b < 4; ++b) { rmin[a][b] = 3.4e38f; ridx[a][b] = 0; }

  // prologue: fill buffer 0 with step 0 (only place vmcnt hits 0 cold)
  stage(0, 0);
  asm volatile("s_waitcnt vmcnt(0)" ::: "memory");
  __builtin_amdgcn_s_barrier();

  for (int nt = 0; nt < NTILES; ++nt) {
    const int n0 = ns0 + nt * BN;
    f32x4 acc[4][8];
#pragma unroll
    for (int a = 0; a < 4; ++a)
#pragma unroll
      for (int b = 0; b < 8; ++b) {
        f32x4 zz = {0.f, 0.f, 0.f, 0.f};
        acc[a][b] = zz;
      }

#pragma unroll 1
    for (int k8 = 0; k8 < 8; ++k8) {
      const int s = nt * 8 + k8;
      const int cur = s & 1;

      // B_a: all waves' reads of buf[cur^1] (step s-1) are retired
      __builtin_amdgcn_s_barrier();
      if (s + 1 < NSTEPS) {
        stage(cur ^ 1, s + 1);                           // 8 new loads
        asm volatile("s_waitcnt vmcnt(8)" ::: "memory"); // retire stage(s)
      } else {
        asm volatile("s_waitcnt vmcnt(0)" ::: "memory"); // last step: drain
      }
      // B_b: everyone's stage(s) writes are visible
      __builtin_amdgcn_s_barrier();
      __builtin_amdgcn_sched_barrier(0);

      bf16x8 ah[4], al[4];
#pragma unroll
      for (int mi = 0; mi < 4; ++mi) {
        const int r = wm * 64 + mi * 16 + l15;
        const int off = r * BK + rd_sw;            // swizzled read
        ah[mi] = *(const bf16x8*)&Ahs[cur][off];
        al[mi] = *(const bf16x8*)&Als[cur][off];
      }
      __builtin_amdgcn_s_setprio(1);
      // ---- quad 0: ni = 0..3 (B frags capped at 32 VGPRs live) ----
      {
        bf16x8 bh[4], bl[4];
#pragma unroll
        for (int nq = 0; nq < 4; ++nq) {
          const int r = wn * 128 + nq * 16 + l15;
          const int off = r * BK + rd_sw;          // swizzled read
          bh[nq] = *(const bf16x8*)&Bhs[cur][off];
          bl[nq] = *(const bf16x8*)&Bls[cur][off];
        }
        // 3 passes; per-acc order hh -> hl -> lh (bitwise-identical)
#pragma unroll
        for (int nq = 0; nq < 4; ++nq)
#pragma unroll
          for (int mi = 0; mi < 4; ++mi)
            MFMA_AGPR(acc[mi][nq], ah[mi], bh[nq]);
#pragma unroll
        for (int nq = 0; nq < 4; ++nq)
#pragma unroll
          for (int mi = 0; mi < 4; ++mi)
            MFMA_AGPR(acc[mi][nq], ah[mi], bl[nq]);
#pragma unroll
        for (int nq = 0; nq < 4; ++nq)
#pragma unroll
          for (int mi = 0; mi < 4; ++mi)
            MFMA_AGPR(acc[mi][nq], al[mi], bh[nq]);
      }
      __builtin_amdgcn_sched_barrier(0);  // do NOT hoist quad-1 B loads
      // ---- quad 1: ni = 4..7 ----
      {
        bf16x8 bh[4], bl[4];
#pragma unroll
        for (int nq = 0; nq < 4; ++nq) {
          const int r = wn * 128 + (4 + nq) * 16 + l15;
          const int off = r * BK + rd_sw;          // swizzled read
          bh[nq] = *(const bf16x8*)&Bhs[cur][off];
          bl[nq] = *(const bf16x8*)&Bls[cur][off];
        }
#pragma unroll
        for (int nq = 0; nq < 4; ++nq)
#pragma unroll
          for (int mi = 0; mi < 4; ++mi)
            MFMA_AGPR(acc[mi][4 + nq], ah[mi], bh[nq]);
#pragma unroll
        for (int nq = 0; nq < 4; ++nq)
#pragma unroll
          for (int mi = 0; mi < 4; ++mi)
            MFMA_AGPR(acc[mi][4 + nq], ah[mi], bl[nq]);
#pragma unroll
        for (int nq = 0; nq < 4; ++nq)
#pragma unroll
          for (int mi = 0; mi < 4; ++mi)
            MFMA_AGPR(acc[mi][4 + nq], al[mi], bh[nq]);
      }
      __builtin_amdgcn_s_setprio(0);
    }

    // epilogue: dist = (zn + cn) - 2*dot, np op order; cols ascending in ni
    // per (mi,i), so tie-break (strict <, first idx wins) is unchanged.
    float cnv[8];
#pragma unroll
    for (int ni = 0; ni < 8; ++ni)
      cnv[ni] = cnorm[n0 + wn * 128 + ni * 16 + l15];
#pragma unroll
    for (int mi = 0; mi < 4; ++mi) {
      float zr[4];
#pragma unroll
      for (int i = 0; i < 4; ++i)
        zr[i] = znorm[m0 + wm * 64 + mi * 16 + lg * 4 + i];
#pragma unroll
      for (int ni = 0; ni < 8; ++ni) {
        const int col = n0 + wn * 128 + ni * 16 + l15;
        const float cn = cnv[ni];
#pragma unroll
        for (int i = 0; i < 4; ++i) {
          const float s = __fadd_rn(zr[i], cn);
          const float v = __fsub_rn(s, __fmul_rn(2.0f, acc[mi][ni][i]));
          if (v < rmin[mi][i]) { rmin[mi][i] = v; ridx[mi][i] = col; }  // strict <
        }
      }
    }
  }
  // 16-lane butterfly reduce (C/D: col=lane&15, row=(lane>>4)*4+i)
#pragma unroll
  for (int mi = 0; mi < 4; ++mi)
#pragma unroll
    for (int i = 0; i < 4; ++i) {
      float v = rmin[mi][i];
      int ix = ridx[mi][i];
#pragma unroll
      for (int d = 1; d < 16; d <<= 1) {
        float ov = __shfl_xor(v, d);
        int oi = __shfl_xor(ix, d);
        if (ov < v || (ov == v && oi < ix)) { v = ov; ix = oi; }
      }
      if (l15 == 0) {
        const int row = m0 + wm * 64 + mi * 16 + lg * 4 + i;
        const int part = spl * 2 + wn;   // per-(split, wn) slot: 0..15
        pval[(size_t)part * NQ + row] = v;
        pidx[(size_t)part * NQ + row] = ix;
      }
    }
}

// ---------- K3: combine partials, gather quantized, loss partial ----------
__global__ __launch_bounds__(256) void finalize_kernel(
    const float* __restrict__ pval, const int* __restrict__ pidx,
    const float* __restrict__ qc, const float* __restrict__ z,
    float* __restrict__ out, float* __restrict__ loss_acc) {
  __shared__ int sidx[8];
  __shared__ float red[256];
  const int bid = blockIdx.x;   // 2048 blocks * 8 rows
  const int t = threadIdx.x;
  if (t < 8) {
    const int row = bid * 8 + t;
    float best = pval[row];
    int bi = pidx[row];
    for (int s2 = 1; s2 < NPART; ++s2) {
      float v = pval[(size_t)s2 * NQ + row];
      int ix = pidx[(size_t)s2 * NQ + row];
      if (v < best || (v == best && ix < bi)) { best = v; bi = ix; }
    }
    sidx[t] = bi;
    out[4194305 + row] = (float)bi;   // encoding_indices as f32
  }
  __syncthreads();
  float d2 = 0.f;
#pragma unroll
  for (int r = 0; r < 8; ++r) {
    const int row = bid * 8 + r;
    const int ix = sidx[r];
    const float q = qc[(size_t)ix * 256 + t];
    const float zz = z[(size_t)row * 256 + t];
    out[(size_t)row * 256 + t] = q;   // STE output == quantized value-wise
    const float d = q - zz;
    d2 += d * d;
  }
  red[t] = d2;
  for (int st = 128; st; st >>= 1) {
    __syncthreads();
    if (t < st) red[t] += red[t + st];
  }
  if (t == 0) atomicAdd(loss_acc, red[0]);
}

// ---------- K4: scalar loss write ----------
__global__ void write_loss_kernel(const float* __restrict__ loss_acc, float* __restrict__ out) {
  // commitment_loss == codebook_loss numerically -> vq_loss = 1.25 * mean
  out[4194304] = 1.25f * loss_acc[0] / 4194304.0f;
}

// ---------- launch ----------
extern "C" void kernel_launch(void* const* d_in, const int* in_sizes, int n_in,
                              void* d_out, int out_size, void* d_ws, size_t ws_size,
                              hipStream_t stream) {
  const float* z = (const float*)d_in[0];
  const float* cb = (const float*)d_in[1];
  const float* W = (const float*)d_in[2];
  const float* bias = (const float*)d_in[3];
  float* out = (float*)d_out;
  char* ws = (char*)d_ws;

  constexpr size_t OFF_QC = 0;                      // 16 MB fp32 quant_codebook
  constexpr size_t OFF_AH = OFF_QC + 16777216;      // 8 MB each
  constexpr size_t OFF_AL = OFF_AH + 8388608;
  constexpr size_t OFF_BH = OFF_AL + 8388608;
  constexpr size_t OFF_BL = OFF_BH + 8388608;
  constexpr size_t OFF_CN = OFF_BL + 8388608;       // 64 KB code norms
  constexpr size_t OFF_ZN = OFF_CN + 65536;         // 64 KB query norms
  constexpr size_t OFF_PV = OFF_ZN + 65536;         // 1 MB partial vals (16 sets)
  constexpr size_t OFF_PI = OFF_PV + 1048576;       // 1 MB partial idx
  constexpr size_t OFF_ACC = OFF_PI + 1048576;      // 4 B loss accumulator

  float* qc = (float*)(ws + OFF_QC);
  u16* Ah = (u16*)(ws + OFF_AH);
  u16* Al = (u16*)(ws + OFF_AL);
  u16* Bh = (u16*)(ws + OFF_BH);
  u16* Bl = (u16*)(ws + OFF_BL);
  float* cn = (float*)(ws + OFF_CN);
  float* zn = (float*)(ws + OFF_ZN);
  float* pv = (float*)(ws + OFF_PV);
  int* pi = (int*)(ws + OFF_PI);
  float* lacc = (float*)(ws + OFF_ACC);

  hipMemsetAsync(lacc, 0, 4, stream);
  split_z_norm_kernel<<<NQ / 32, 256, 0, stream>>>(z, Ah, Al, zn);
  qc_gemm_kernel<<<256, 256, 0, stream>>>(cb, W, bias, qc, Bh, Bl);
  norm256_kernel<<<NC / 32, 256, 0, stream>>>(qc, cn);
  vq_argmin_kernel<<<(NQ / BM) * NSPLIT, 512, 0, stream>>>(Ah, Al, Bh, Bl, cn, zn, pv, pi);
  finalize_kernel<<<NQ / 8, 256, 0, stream>>>(pv, pi, qc, z, out, lacc);
  write_loss_kernel<<<1, 1, 0, stream>>>(lacc, out);
}